// Round 1
// baseline (1207.728 us; speedup 1.0000x reference)
//
#include <hip/hip_runtime.h>
#include <cstddef>

#define TB 4
#define TS 2048
#define TDM 512
#define TH 8
#define TDK 64

static constexpr float LN_EPS = 1e-5f;

// ---------------- block-wide reductions (256 threads = 4 waves) ----------------
__device__ __forceinline__ float block_max256(float v) {
    __shared__ float sc[4];
    #pragma unroll
    for (int o = 32; o > 0; o >>= 1) v = fmaxf(v, __shfl_down(v, o));
    if ((threadIdx.x & 63) == 0) sc[threadIdx.x >> 6] = v;
    __syncthreads();
    v = fmaxf(fmaxf(sc[0], sc[1]), fmaxf(sc[2], sc[3]));
    __syncthreads();
    return v;
}

__device__ __forceinline__ float block_sum256(float v) {
    __shared__ float sc[4];
    #pragma unroll
    for (int o = 32; o > 0; o >>= 1) v += __shfl_down(v, o);
    if ((threadIdx.x & 63) == 0) sc[threadIdx.x >> 6] = v;
    __syncthreads();
    v = sc[0] + sc[1] + sc[2] + sc[3];
    __syncthreads();
    return v;
}

// ---------------- K1: input projections  X(8192x512) @ W(512x512) ----------------
// z = 0/1/2 selects (q,w_q)->Q, (k,w_k)->K, (v,w_v)->V; output layout [b][h][s][d]
__global__ __launch_bounds__(256) void proj_kernel(
    const float* __restrict__ qin, const float* __restrict__ kin, const float* __restrict__ vin,
    const float* __restrict__ wq,  const float* __restrict__ wk,  const float* __restrict__ wv,
    float* __restrict__ Qh, float* __restrict__ Kh, float* __restrict__ Vh)
{
    const int which = blockIdx.z;
    const float* X = which == 0 ? qin : (which == 1 ? kin : vin);
    const float* W = which == 0 ? wq  : (which == 1 ? wk  : wv);
    float*       O = which == 0 ? Qh  : (which == 1 ? Kh  : Vh);

    __shared__ float As[16][64];   // [k][m]
    __shared__ float Bs[16][64];   // [k][n]
    const int m0 = blockIdx.y * 64;
    const int n0 = blockIdx.x * 64;
    const int t  = threadIdx.x;
    const int tx = t & 15, ty = t >> 4;

    float acc[4][4] = {};
    for (int k0 = 0; k0 < TDM; k0 += 16) {
        {
            const int row = t >> 2;            // 0..63
            const int kq  = (t & 3) * 4;       // 0,4,8,12
            float4 a4 = *(const float4*)&X[(size_t)(m0 + row) * TDM + k0 + kq];
            As[kq+0][row] = a4.x; As[kq+1][row] = a4.y; As[kq+2][row] = a4.z; As[kq+3][row] = a4.w;
        }
        {
            const int kk  = t >> 4;            // 0..15
            const int col = (t & 15) * 4;
            *(float4*)&Bs[kk][col] = *(const float4*)&W[(size_t)(k0 + kk) * TDM + n0 + col];
        }
        __syncthreads();
        #pragma unroll
        for (int kk = 0; kk < 16; ++kk) {
            float a[4], bb[4];
            #pragma unroll
            for (int i = 0; i < 4; ++i) a[i]  = As[kk][ty*4 + i];
            #pragma unroll
            for (int j = 0; j < 4; ++j) bb[j] = Bs[kk][tx*4 + j];
            #pragma unroll
            for (int i = 0; i < 4; ++i)
                #pragma unroll
                for (int j = 0; j < 4; ++j)
                    acc[i][j] = fmaf(a[i], bb[j], acc[i][j]);
        }
        __syncthreads();
    }
    const int h = n0 >> 6;                 // tile is 64-aligned -> one head per tile
    #pragma unroll
    for (int i = 0; i < 4; ++i) {
        const int m = m0 + ty*4 + i;
        const int b = m >> 11, s = m & 2047;
        float4 r = make_float4(acc[i][0], acc[i][1], acc[i][2], acc[i][3]);
        *(float4*)&O[(((size_t)(b*TH + h) * TS + s) * TDK) + tx*4] = r;
    }
}

// ---------------- K2: scores = Qh @ Kh^T / 8, masked -> attn region ----------------
__global__ __launch_bounds__(256) void score_kernel(
    const float* __restrict__ Qh, const float* __restrict__ Kh,
    const int* __restrict__ mask, float* __restrict__ attn)
{
    const int bh = blockIdx.z;          // b*8 + h
    const int b  = bh >> 3;
    const int m0 = blockIdx.y * 64;
    const int n0 = blockIdx.x * 64;
    __shared__ float As[64][64];        // [k][m]
    __shared__ float Bs[64][64];        // [k][n]
    const int t  = threadIdx.x;
    const int tx = t & 15, ty = t >> 4;

    {
        const int r  = t >> 2;
        const int kq = (t & 3) * 4;
        #pragma unroll
        for (int p = 0; p < 4; ++p) {
            const int kk = kq + p * 16;
            float4 a4 = *(const float4*)&Qh[((size_t)bh * TS + m0 + r) * TDK + kk];
            As[kk+0][r] = a4.x; As[kk+1][r] = a4.y; As[kk+2][r] = a4.z; As[kk+3][r] = a4.w;
            float4 b4 = *(const float4*)&Kh[((size_t)bh * TS + n0 + r) * TDK + kk];
            Bs[kk+0][r] = b4.x; Bs[kk+1][r] = b4.y; Bs[kk+2][r] = b4.z; Bs[kk+3][r] = b4.w;
        }
    }
    __syncthreads();

    float acc[4][4] = {};
    #pragma unroll 8
    for (int kk = 0; kk < 64; ++kk) {
        float a[4], bb[4];
        #pragma unroll
        for (int i = 0; i < 4; ++i) a[i]  = As[kk][ty*4 + i];
        #pragma unroll
        for (int j = 0; j < 4; ++j) bb[j] = Bs[kk][tx*4 + j];
        #pragma unroll
        for (int i = 0; i < 4; ++i)
            #pragma unroll
            for (int j = 0; j < 4; ++j)
                acc[i][j] = fmaf(a[i], bb[j], acc[i][j]);
    }

    const float inv_scale = 0.125f;     // 1/sqrt(64)
    #pragma unroll
    for (int i = 0; i < 4; ++i) {
        const int m = m0 + ty*4 + i;
        const int4 mk = *(const int4*)&mask[((size_t)b * TS + m) * TS + n0 + tx*4];
        float4 r;
        r.x = mk.x ? -1e9f : acc[i][0] * inv_scale;
        r.y = mk.y ? -1e9f : acc[i][1] * inv_scale;
        r.z = mk.z ? -1e9f : acc[i][2] * inv_scale;
        r.w = mk.w ? -1e9f : acc[i][3] * inv_scale;
        *(float4*)&attn[((size_t)bh * TS + m) * TS + n0 + tx*4] = r;
    }
}

// ---------------- K3: in-place row softmax over attn (rows of 2048) ----------------
__global__ __launch_bounds__(256) void softmax_kernel(float* __restrict__ attn)
{
    float* p = attn + (size_t)blockIdx.x * TS;
    const int t = threadIdx.x;
    float4 v0 = *(float4*)&p[t*4];
    float4 v1 = *(float4*)&p[1024 + t*4];
    float mx = fmaxf(fmaxf(fmaxf(v0.x, v0.y), fmaxf(v0.z, v0.w)),
                     fmaxf(fmaxf(v1.x, v1.y), fmaxf(v1.z, v1.w)));
    mx = block_max256(mx);
    v0.x = __expf(v0.x - mx); v0.y = __expf(v0.y - mx);
    v0.z = __expf(v0.z - mx); v0.w = __expf(v0.w - mx);
    v1.x = __expf(v1.x - mx); v1.y = __expf(v1.y - mx);
    v1.z = __expf(v1.z - mx); v1.w = __expf(v1.w - mx);
    float s = (v0.x + v0.y + v0.z + v0.w) + (v1.x + v1.y + v1.z + v1.w);
    s = block_sum256(s);
    const float inv = 1.0f / s;
    v0.x *= inv; v0.y *= inv; v0.z *= inv; v0.w *= inv;
    v1.x *= inv; v1.y *= inv; v1.z *= inv; v1.w *= inv;
    *(float4*)&p[t*4] = v0;
    *(float4*)&p[1024 + t*4] = v1;
}

// ---------------- K4: heads = attn @ Vh  -> written into out region [b][s][h*64+d] ----------------
__global__ __launch_bounds__(256) void pv_kernel(
    const float* __restrict__ attn, const float* __restrict__ Vh, float* __restrict__ heads)
{
    const int bh = blockIdx.z;
    const int b  = bh >> 3, h = bh & 7;
    const int m0 = blockIdx.y * 64;
    __shared__ float As[16][64];  // [k][m]
    __shared__ float Bs[16][64];  // [k][n]
    const int t  = threadIdx.x;
    const int tx = t & 15, ty = t >> 4;

    float acc[4][4] = {};
    for (int k0 = 0; k0 < TS; k0 += 16) {
        {
            const int r  = t >> 2;
            const int kq = (t & 3) * 4;
            float4 a4 = *(const float4*)&attn[((size_t)bh * TS + m0 + r) * TS + k0 + kq];
            As[kq+0][r] = a4.x; As[kq+1][r] = a4.y; As[kq+2][r] = a4.z; As[kq+3][r] = a4.w;
        }
        {
            const int kk  = t >> 4;
            const int col = (t & 15) * 4;
            *(float4*)&Bs[kk][col] = *(const float4*)&Vh[((size_t)bh * TS + k0 + kk) * TDK + col];
        }
        __syncthreads();
        #pragma unroll
        for (int kk = 0; kk < 16; ++kk) {
            float a[4], bb[4];
            #pragma unroll
            for (int i = 0; i < 4; ++i) a[i]  = As[kk][ty*4 + i];
            #pragma unroll
            for (int j = 0; j < 4; ++j) bb[j] = Bs[kk][tx*4 + j];
            #pragma unroll
            for (int i = 0; i < 4; ++i)
                #pragma unroll
                for (int j = 0; j < 4; ++j)
                    acc[i][j] = fmaf(a[i], bb[j], acc[i][j]);
        }
        __syncthreads();
    }
    #pragma unroll
    for (int i = 0; i < 4; ++i) {
        const int m = m0 + ty*4 + i;
        float4 r = make_float4(acc[i][0], acc[i][1], acc[i][2], acc[i][3]);
        *(float4*)&heads[((size_t)b * TS + m) * TDM + h*TDK + tx*4] = r;
    }
}

// ---------------- K5: out = LN(heads @ w_o + q), in place on out region ----------------
__global__ __launch_bounds__(256) void outln_kernel(
    const float* __restrict__ wo, const float* __restrict__ qin,
    const float* __restrict__ g,  const float* __restrict__ be,
    float* __restrict__ out)
{
    const int m = blockIdx.x;                 // 0..8191
    float* row = out + (size_t)m * TDM;
    __shared__ float hrow[TDM];
    const int t = threadIdx.x;

    ((float2*)hrow)[t] = ((const float2*)row)[t];   // 256 x 8B = 512 floats
    __syncthreads();

    float acc0 = 0.f, acc1 = 0.f;
    #pragma unroll 8
    for (int k = 0; k < TDM; ++k) {
        const float hv = hrow[k];
        acc0 = fmaf(hv, wo[(size_t)k * TDM + t],       acc0);
        acc1 = fmaf(hv, wo[(size_t)k * TDM + t + 256], acc1);
    }
    acc0 += qin[(size_t)m * TDM + t];
    acc1 += qin[(size_t)m * TDM + t + 256];

    float s  = block_sum256(acc0 + acc1);
    float s2 = block_sum256(acc0*acc0 + acc1*acc1);
    const float mu  = s * (1.0f / TDM);
    const float var = s2 * (1.0f / TDM) - mu * mu;
    const float inv = rsqrtf(var + LN_EPS);

    row[t]       = (acc0 - mu) * inv * g[t]       + be[t];
    row[t + 256] = (acc1 - mu) * inv * g[t + 256] + be[t + 256];
}

// ---------------- launch ----------------
extern "C" void kernel_launch(void* const* d_in, const int* in_sizes, int n_in,
                              void* d_out, int out_size, void* d_ws, size_t ws_size,
                              hipStream_t stream) {
    const float* q   = (const float*)d_in[0];
    const float* k   = (const float*)d_in[1];
    const float* v   = (const float*)d_in[2];
    const float* wq  = (const float*)d_in[3];
    const float* wk  = (const float*)d_in[4];
    const float* wv  = (const float*)d_in[5];
    const float* wo  = (const float*)d_in[6];
    const float* g   = (const float*)d_in[7];
    const float* be  = (const float*)d_in[8];
    const int*   msk = (const int*)d_in[9];

    float* out  = (float*)d_out;
    float* attn = out + (size_t)TB * TS * TDM;          // 4,194,304 floats in
    float* Qh   = (float*)d_ws;
    float* Kh   = Qh + (size_t)TB * TH * TS * TDK;      // +16 MB
    float* Vh   = Kh + (size_t)TB * TH * TS * TDK;      // +16 MB

    proj_kernel   <<<dim3(TDM/64, (TB*TS)/64, 3), 256, 0, stream>>>(q, k, v, wq, wk, wv, Qh, Kh, Vh);
    score_kernel  <<<dim3(TS/64, TS/64, TB*TH),   256, 0, stream>>>(Qh, Kh, msk, attn);
    softmax_kernel<<<dim3(TB*TH*TS),              256, 0, stream>>>(attn);
    pv_kernel     <<<dim3(1, TS/64, TB*TH),       256, 0, stream>>>(attn, Vh, out);
    outln_kernel  <<<dim3(TB*TS),                 256, 0, stream>>>(wo, q, g, be, out);
}

// Round 2
// 926.995 us; speedup vs baseline: 1.3028x; 1.3028x over previous
//
#include <hip/hip_runtime.h>
#include <cstddef>

#define TB 4
#define TS 2048
#define TDM 512
#define TH 8
#define TDK 64

static constexpr float LN_EPS = 1e-5f;

// ---------------- block-wide sum reduction (256 threads = 4 waves) ----------------
__device__ __forceinline__ float block_sum256(float v) {
    __shared__ float sc[4];
    #pragma unroll
    for (int o = 32; o > 0; o >>= 1) v += __shfl_down(v, o);
    if ((threadIdx.x & 63) == 0) sc[threadIdx.x >> 6] = v;
    __syncthreads();
    v = sc[0] + sc[1] + sc[2] + sc[3];
    __syncthreads();
    return v;
}

// ---------------- K1: input projections  X(8192x512) @ W(512x512) ----------------
// z = 0/1/2 selects (q,w_q)->Q, (k,w_k)->K, (v,w_v)->V; output layout [b][h][s][d]
__global__ __launch_bounds__(256) void proj_kernel(
    const float* __restrict__ qin, const float* __restrict__ kin, const float* __restrict__ vin,
    const float* __restrict__ wq,  const float* __restrict__ wk,  const float* __restrict__ wv,
    float* __restrict__ Qh, float* __restrict__ Kh, float* __restrict__ Vh)
{
    const int which = blockIdx.z;
    const float* X = which == 0 ? qin : (which == 1 ? kin : vin);
    const float* W = which == 0 ? wq  : (which == 1 ? wk  : wv);
    float*       O = which == 0 ? Qh  : (which == 1 ? Kh  : Vh);

    __shared__ float As[16][64];   // [k][m]
    __shared__ float Bs[16][64];   // [k][n]
    const int m0 = blockIdx.y * 64;
    const int n0 = blockIdx.x * 64;
    const int t  = threadIdx.x;
    const int tx = t & 15, ty = t >> 4;

    float acc[4][4] = {};
    for (int k0 = 0; k0 < TDM; k0 += 16) {
        {
            const int row = t >> 2;            // 0..63
            const int kq  = (t & 3) * 4;       // 0,4,8,12
            float4 a4 = *(const float4*)&X[(size_t)(m0 + row) * TDM + k0 + kq];
            As[kq+0][row] = a4.x; As[kq+1][row] = a4.y; As[kq+2][row] = a4.z; As[kq+3][row] = a4.w;
        }
        {
            const int kk  = t >> 4;            // 0..15
            const int col = (t & 15) * 4;
            *(float4*)&Bs[kk][col] = *(const float4*)&W[(size_t)(k0 + kk) * TDM + n0 + col];
        }
        __syncthreads();
        #pragma unroll
        for (int kk = 0; kk < 16; ++kk) {
            float a[4], bb[4];
            #pragma unroll
            for (int i = 0; i < 4; ++i) a[i]  = As[kk][ty*4 + i];
            #pragma unroll
            for (int j = 0; j < 4; ++j) bb[j] = Bs[kk][tx*4 + j];
            #pragma unroll
            for (int i = 0; i < 4; ++i)
                #pragma unroll
                for (int j = 0; j < 4; ++j)
                    acc[i][j] = fmaf(a[i], bb[j], acc[i][j]);
        }
        __syncthreads();
    }
    const int h = n0 >> 6;                 // tile is 64-aligned -> one head per tile
    #pragma unroll
    for (int i = 0; i < 4; ++i) {
        const int m = m0 + ty*4 + i;
        const int b = m >> 11, s = m & 2047;
        float4 r = make_float4(acc[i][0], acc[i][1], acc[i][2], acc[i][3]);
        *(float4*)&O[(((size_t)(b*TH + h) * TS + s) * TDK) + tx*4] = r;
    }
}

// ---------------- K2: E = exp(QK^T/8) masked->0, write E, atomic row sums ----------------
__global__ __launch_bounds__(256) void score_exp_kernel(
    const float* __restrict__ Qh, const float* __restrict__ Kh,
    const int* __restrict__ mask, float* __restrict__ attn,
    float* __restrict__ rowsum)
{
    const int bh = blockIdx.z;          // b*8 + h
    const int b  = bh >> 3;
    const int m0 = blockIdx.y * 64;
    const int n0 = blockIdx.x * 64;
    __shared__ float As[64][64];        // [k][m]
    __shared__ float Bs[64][64];        // [k][n]
    const int t  = threadIdx.x;
    const int tx = t & 15, ty = t >> 4;

    {
        const int r  = t >> 2;
        const int kq = (t & 3) * 4;
        #pragma unroll
        for (int p = 0; p < 4; ++p) {
            const int kk = kq + p * 16;
            float4 a4 = *(const float4*)&Qh[((size_t)bh * TS + m0 + r) * TDK + kk];
            As[kk+0][r] = a4.x; As[kk+1][r] = a4.y; As[kk+2][r] = a4.z; As[kk+3][r] = a4.w;
            float4 b4 = *(const float4*)&Kh[((size_t)bh * TS + n0 + r) * TDK + kk];
            Bs[kk+0][r] = b4.x; Bs[kk+1][r] = b4.y; Bs[kk+2][r] = b4.z; Bs[kk+3][r] = b4.w;
        }
    }
    __syncthreads();

    float acc[4][4] = {};
    #pragma unroll 8
    for (int kk = 0; kk < 64; ++kk) {
        float a[4], bb[4];
        #pragma unroll
        for (int i = 0; i < 4; ++i) a[i]  = As[kk][ty*4 + i];
        #pragma unroll
        for (int j = 0; j < 4; ++j) bb[j] = Bs[kk][tx*4 + j];
        #pragma unroll
        for (int i = 0; i < 4; ++i)
            #pragma unroll
            for (int j = 0; j < 4; ++j)
                acc[i][j] = fmaf(a[i], bb[j], acc[i][j]);
    }

    const float inv_scale = 0.125f;     // 1/sqrt(64)
    float rs[4];
    #pragma unroll
    for (int i = 0; i < 4; ++i) {
        const int m = m0 + ty*4 + i;
        const int4 mk = *(const int4*)&mask[((size_t)b * TS + m) * TS + n0 + tx*4];
        float4 r;
        r.x = mk.x ? 0.0f : __expf(acc[i][0] * inv_scale);
        r.y = mk.y ? 0.0f : __expf(acc[i][1] * inv_scale);
        r.z = mk.z ? 0.0f : __expf(acc[i][2] * inv_scale);
        r.w = mk.w ? 0.0f : __expf(acc[i][3] * inv_scale);
        *(float4*)&attn[((size_t)bh * TS + m) * TS + n0 + tx*4] = r;
        rs[i] = r.x + r.y + r.z + r.w;
    }
    // reduce rs[i] across the 16 tx lanes (same ty group stays within a wave)
    #pragma unroll
    for (int i = 0; i < 4; ++i) {
        #pragma unroll
        for (int o = 8; o > 0; o >>= 1) rs[i] += __shfl_down(rs[i], o);
    }
    if (tx == 0) {
        #pragma unroll
        for (int i = 0; i < 4; ++i)
            atomicAdd(&rowsum[(size_t)bh * TS + m0 + ty*4 + i], rs[i]);
    }
}

// ---------------- K3: heads = (E @ Vh) * inv_sum; also attn <- E * inv_sum ----------------
__global__ __launch_bounds__(256) void pv_norm_kernel(
    float* __restrict__ attn, const float* __restrict__ Vh,
    const float* __restrict__ rowsum, float* __restrict__ heads)
{
    const int bh = blockIdx.z;
    const int b  = bh >> 3, h = bh & 7;
    const int m0 = blockIdx.y * 64;
    __shared__ float As[16][64];  // [k][m]
    __shared__ float Bs[16][64];  // [k][n]
    __shared__ float inv_s[64];
    const int t  = threadIdx.x;
    const int tx = t & 15, ty = t >> 4;

    if (t < 64) inv_s[t] = 1.0f / rowsum[(size_t)bh * TS + m0 + t];
    __syncthreads();

    float acc[4][4] = {};
    for (int k0 = 0; k0 < TS; k0 += 16) {
        {
            const int r  = t >> 2;
            const int kq = (t & 3) * 4;
            float* ap = &attn[((size_t)bh * TS + m0 + r) * TS + k0 + kq];
            float4 a4 = *(const float4*)ap;
            As[kq+0][r] = a4.x; As[kq+1][r] = a4.y; As[kq+2][r] = a4.z; As[kq+3][r] = a4.w;
            const float is = inv_s[r];
            float4 w4 = make_float4(a4.x * is, a4.y * is, a4.z * is, a4.w * is);
            *(float4*)ap = w4;                         // normalized attn output
        }
        {
            const int kk  = t >> 4;
            const int col = (t & 15) * 4;
            *(float4*)&Bs[kk][col] = *(const float4*)&Vh[((size_t)bh * TS + k0 + kk) * TDK + col];
        }
        __syncthreads();
        #pragma unroll
        for (int kk = 0; kk < 16; ++kk) {
            float a[4], bb[4];
            #pragma unroll
            for (int i = 0; i < 4; ++i) a[i]  = As[kk][ty*4 + i];
            #pragma unroll
            for (int j = 0; j < 4; ++j) bb[j] = Bs[kk][tx*4 + j];
            #pragma unroll
            for (int i = 0; i < 4; ++i)
                #pragma unroll
                for (int j = 0; j < 4; ++j)
                    acc[i][j] = fmaf(a[i], bb[j], acc[i][j]);
        }
        __syncthreads();
    }
    #pragma unroll
    for (int i = 0; i < 4; ++i) {
        const int m = m0 + ty*4 + i;
        const float is = inv_s[ty*4 + i];
        float4 r = make_float4(acc[i][0]*is, acc[i][1]*is, acc[i][2]*is, acc[i][3]*is);
        *(float4*)&heads[((size_t)b * TS + m) * TDM + h*TDK + tx*4] = r;
    }
}

// ---------------- K4: out = heads @ w_o + q  (tiled GEMM) ----------------
__global__ __launch_bounds__(256) void outgemm_kernel(
    const float* __restrict__ heads, const float* __restrict__ wo,
    const float* __restrict__ qin, float* __restrict__ out)
{
    __shared__ float As[16][64];   // [k][m]
    __shared__ float Bs[16][64];   // [k][n]
    const int m0 = blockIdx.y * 64;
    const int n0 = blockIdx.x * 64;
    const int t  = threadIdx.x;
    const int tx = t & 15, ty = t >> 4;

    float acc[4][4] = {};
    for (int k0 = 0; k0 < TDM; k0 += 16) {
        {
            const int row = t >> 2;
            const int kq  = (t & 3) * 4;
            float4 a4 = *(const float4*)&heads[(size_t)(m0 + row) * TDM + k0 + kq];
            As[kq+0][row] = a4.x; As[kq+1][row] = a4.y; As[kq+2][row] = a4.z; As[kq+3][row] = a4.w;
        }
        {
            const int kk  = t >> 4;
            const int col = (t & 15) * 4;
            *(float4*)&Bs[kk][col] = *(const float4*)&wo[(size_t)(k0 + kk) * TDM + n0 + col];
        }
        __syncthreads();
        #pragma unroll
        for (int kk = 0; kk < 16; ++kk) {
            float a[4], bb[4];
            #pragma unroll
            for (int i = 0; i < 4; ++i) a[i]  = As[kk][ty*4 + i];
            #pragma unroll
            for (int j = 0; j < 4; ++j) bb[j] = Bs[kk][tx*4 + j];
            #pragma unroll
            for (int i = 0; i < 4; ++i)
                #pragma unroll
                for (int j = 0; j < 4; ++j)
                    acc[i][j] = fmaf(a[i], bb[j], acc[i][j]);
        }
        __syncthreads();
    }
    #pragma unroll
    for (int i = 0; i < 4; ++i) {
        const int m = m0 + ty*4 + i;
        float4 q4 = *(const float4*)&qin[(size_t)m * TDM + n0 + tx*4];
        float4 r = make_float4(acc[i][0] + q4.x, acc[i][1] + q4.y,
                               acc[i][2] + q4.z, acc[i][3] + q4.w);
        *(float4*)&out[(size_t)m * TDM + n0 + tx*4] = r;
    }
}

// ---------------- K5: in-place row LayerNorm ----------------
__global__ __launch_bounds__(256) void ln_kernel(
    float* __restrict__ out, const float* __restrict__ g, const float* __restrict__ be)
{
    const int m = blockIdx.x;                 // 0..8191
    float* row = out + (size_t)m * TDM;
    const int t = threadIdx.x;

    float2 v = ((const float2*)row)[t];       // 256 x 8B = 512 floats
    float s  = block_sum256(v.x + v.y);
    float s2 = block_sum256(v.x*v.x + v.y*v.y);
    const float mu  = s * (1.0f / TDM);
    const float var = s2 * (1.0f / TDM) - mu * mu;
    const float inv = rsqrtf(var + LN_EPS);

    float2 gg = ((const float2*)g)[t];
    float2 bb = ((const float2*)be)[t];
    float2 r;
    r.x = (v.x - mu) * inv * gg.x + bb.x;
    r.y = (v.y - mu) * inv * gg.y + bb.y;
    ((float2*)row)[t] = r;
}

// ---------------- launch ----------------
extern "C" void kernel_launch(void* const* d_in, const int* in_sizes, int n_in,
                              void* d_out, int out_size, void* d_ws, size_t ws_size,
                              hipStream_t stream) {
    const float* q   = (const float*)d_in[0];
    const float* k   = (const float*)d_in[1];
    const float* v   = (const float*)d_in[2];
    const float* wq  = (const float*)d_in[3];
    const float* wk  = (const float*)d_in[4];
    const float* wv  = (const float*)d_in[5];
    const float* wo  = (const float*)d_in[6];
    const float* g   = (const float*)d_in[7];
    const float* be  = (const float*)d_in[8];
    const int*   msk = (const int*)d_in[9];

    float* out  = (float*)d_out;
    float* attn = out + (size_t)TB * TS * TDM;          // 4,194,304 floats in

    const size_t nQKV = (size_t)TB * TH * TS * TDK;     // 4,194,304 floats
    float* Qh     = (float*)d_ws;
    float* Kh     = Qh + nQKV;
    float* Vh     = Kh + nQKV;
    float* rowsum = Vh + nQKV;                          // 32*2048 floats (256 KB)
    float* heads  = Qh;                                 // reuse: Qh dead after score

    hipMemsetAsync(rowsum, 0, (size_t)TB * TH * TS * sizeof(float), stream);

    proj_kernel     <<<dim3(TDM/64, (TB*TS)/64, 3), 256, 0, stream>>>(q, k, v, wq, wk, wv, Qh, Kh, Vh);
    score_exp_kernel<<<dim3(TS/64, TS/64, TB*TH),   256, 0, stream>>>(Qh, Kh, msk, attn, rowsum);
    pv_norm_kernel  <<<dim3(1, TS/64, TB*TH),       256, 0, stream>>>(attn, Vh, rowsum, heads);
    outgemm_kernel  <<<dim3(TDM/64, (TB*TS)/64),    256, 0, stream>>>(heads, wo, q, out);
    ln_kernel       <<<dim3(TB*TS),                 256, 0, stream>>>(out, g, be);
}

// Round 3
// 744.109 us; speedup vs baseline: 1.6231x; 1.2458x over previous
//
#include <hip/hip_runtime.h>
#include <cstddef>

typedef __attribute__((ext_vector_type(8))) short bf16x8;
typedef __attribute__((ext_vector_type(4))) float f32x4;
typedef __attribute__((ext_vector_type(4))) short short4v;
typedef unsigned long long u64;
typedef unsigned int u32;
typedef unsigned short u16;

#define MFMA16 __builtin_amdgcn_mfma_f32_16x16x32_bf16
static constexpr float LN_EPS = 1e-5f;
static constexpr float L2E = 1.44269504f;

__device__ __forceinline__ u16 f2bf(float f) {
    u32 u = __builtin_bit_cast(u32, f);
    return (u16)((u + 0x7FFFu + ((u >> 16) & 1u)) >> 16);
}

// ---------------- block-wide sum (256 threads) ----------------
__device__ __forceinline__ float block_sum256(float v) {
    __shared__ float sc[4];
    #pragma unroll
    for (int o = 32; o > 0; o >>= 1) v += __shfl_down(v, o);
    if ((threadIdx.x & 63) == 0) sc[threadIdx.x >> 6] = v;
    __syncthreads();
    v = sc[0] + sc[1] + sc[2] + sc[3];
    __syncthreads();
    return v;
}

// ---------------- prep: weights fp32 [k][n] -> bf16 Wt [mat][n][k] ----------------
__global__ __launch_bounds__(256) void prepw_kernel(
    const float* __restrict__ wq, const float* __restrict__ wk,
    const float* __restrict__ wv, const float* __restrict__ wo,
    u16* __restrict__ wt)
{
    const int mat = blockIdx.z;
    const float* W = mat == 0 ? wq : mat == 1 ? wk : mat == 2 ? wv : wo;
    const int k0 = blockIdx.x * 64, n0 = blockIdx.y * 64;
    __shared__ u16 ld[64][72];
    const int t = threadIdx.x;
    {
        const int kk = t >> 2;
        #pragma unroll
        for (int j = 0; j < 4; ++j) {
            const int nn = ((t & 3) + j * 4) * 4;
            float4 x = *(const float4*)&W[(size_t)(k0 + kk) * 512 + n0 + nn];
            ld[kk][nn + 0] = f2bf(x.x); ld[kk][nn + 1] = f2bf(x.y);
            ld[kk][nn + 2] = f2bf(x.z); ld[kk][nn + 3] = f2bf(x.w);
        }
    }
    __syncthreads();
    {
        const int n = t & 63, kc = (t >> 6) * 16;
        u16* op = wt + ((size_t)mat * 512 + n0 + n) * 512 + k0 + kc;
        #pragma unroll
        for (int j = 0; j < 4; ++j) {
            short4v v;
            v[0] = ld[kc + j*4 + 0][n]; v[1] = ld[kc + j*4 + 1][n];
            v[2] = ld[kc + j*4 + 2][n]; v[3] = ld[kc + j*4 + 3][n];
            *(short4v*)(op + j * 4) = v;
        }
    }
}

// ---------------- prep: mask int32 -> bit-packed u64 [8192 rows][32 words] ----------------
__global__ __launch_bounds__(256) void prepm_kernel(
    const int* __restrict__ mask, u64* __restrict__ bits)
{
    const int t = threadIdx.x;
    const int row = blockIdx.x * 4 + (t >> 6);
    const int wl = t & 63;
    const int* mrow = mask + (size_t)row * 2048;
    u64* brow = bits + (size_t)row * 32;
    #pragma unroll 8
    for (int it = 0; it < 32; ++it) {
        u64 b = __ballot(mrow[it * 64 + wl] != 0);
        if (wl == 0) brow[it] = b;
    }
}

// ---------------- K1: projections via MFMA. X fp32 @ Wt -> Qh/Kh/Vh bf16 [bh][s][64]
__global__ __launch_bounds__(256) void proj_kernel(
    const float* __restrict__ qin, const float* __restrict__ kin, const float* __restrict__ vin,
    const u16* __restrict__ wt,
    u16* __restrict__ Qh, u16* __restrict__ Kh, u16* __restrict__ Vh)
{
    const int z = blockIdx.z;
    const float* X = z == 0 ? qin : (z == 1 ? kin : vin);
    const u16* W = wt + (size_t)z * 512 * 512;
    u16* O = z == 0 ? Qh : (z == 1 ? Kh : Vh);
    const int m0 = blockIdx.x * 64;
    const int h = blockIdx.y;
    const int t = threadIdx.x, l = t & 63, w = t >> 6;
    const int q = l & 15, G = l >> 4;
    const int wr = w >> 1, wc = w & 1;

    f32x4 acc[2][2] = {};
    for (int k0 = 0; k0 < 512; k0 += 32) {
        bf16x8 af[2], bfr[2];
        #pragma unroll
        for (int mi = 0; mi < 2; ++mi) {
            const float* xp = X + (size_t)(m0 + wr*32 + mi*16 + q) * 512 + k0 + G*8;
            float4 x0 = *(const float4*)xp;
            float4 x1 = *(const float4*)(xp + 4);
            bf16x8 a;
            a[0] = f2bf(x0.x); a[1] = f2bf(x0.y); a[2] = f2bf(x0.z); a[3] = f2bf(x0.w);
            a[4] = f2bf(x1.x); a[5] = f2bf(x1.y); a[6] = f2bf(x1.z); a[7] = f2bf(x1.w);
            af[mi] = a;
        }
        #pragma unroll
        for (int tn = 0; tn < 2; ++tn)
            bfr[tn] = *(const bf16x8*)(W + (size_t)(h*64 + wc*32 + tn*16 + q) * 512 + k0 + G*8);
        #pragma unroll
        for (int mi = 0; mi < 2; ++mi)
            #pragma unroll
            for (int tn = 0; tn < 2; ++tn)
                acc[mi][tn] = MFMA16(af[mi], bfr[tn], acc[mi][tn], 0, 0, 0);
    }
    const float scv = (z == 0) ? 0.125f : 1.0f;   // fold 1/sqrt(64) into Q (exact pow2)
    #pragma unroll
    for (int mi = 0; mi < 2; ++mi)
        #pragma unroll
        for (int tn = 0; tn < 2; ++tn)
            #pragma unroll
            for (int r = 0; r < 4; ++r) {
                const int m = m0 + wr*32 + mi*16 + G*4 + r;
                const int b = m >> 11, s = m & 2047;
                const int d = wc*32 + tn*16 + q;
                O[(((size_t)(b*8 + h) << 11) + s) * 64 + d] = f2bf(acc[mi][tn][r] * scv);
            }
}

// ---------------- V transpose: Vh [bh][s][64] -> Vt [bh][64][2048] ----------------
__global__ __launch_bounds__(256) void vt_kernel(
    const u16* __restrict__ Vh, u16* __restrict__ Vt)
{
    const int bh = blockIdx.y, s0 = blockIdx.x * 64;
    __shared__ u16 ld[64][72];
    const int t = threadIdx.x;
    {
        const int s = t >> 2, dg = (t & 3) * 16;
        const u16* vp = Vh + ((((size_t)bh << 11) + s0 + s) * 64) + dg;
        *(bf16x8*)&ld[s][dg]     = *(const bf16x8*)vp;
        *(bf16x8*)&ld[s][dg + 8] = *(const bf16x8*)(vp + 8);
    }
    __syncthreads();
    {
        const int d = t & 63, sc = (t >> 6) * 16;
        u16* op = Vt + (((size_t)bh << 6) + d) * 2048 + s0 + sc;
        #pragma unroll
        for (int j = 0; j < 4; ++j) {
            short4v v;
            v[0] = ld[sc + j*4 + 0][d]; v[1] = ld[sc + j*4 + 1][d];
            v[2] = ld[sc + j*4 + 2][d]; v[3] = ld[sc + j*4 + 3][d];
            *(short4v*)(op + j * 4) = v;
        }
    }
}

// ---------------- K2 (A): row sums of exp via swapped MFMA S^T = K·Q^T ----------------
__global__ __launch_bounds__(256) void rowsum_kernel(
    const u16* __restrict__ Qh, const u16* __restrict__ Kh,
    const u64* __restrict__ bits, float* __restrict__ invs)
{
    const int qt = blockIdx.x, bh = blockIdx.y;
    const int m0 = qt * 64;
    const int t = threadIdx.x, l = t & 63, w = t >> 6;
    const int q = l & 15, G = l >> 4;
    const int qrow = m0 + w*16 + q;
    const size_t qbase = (((size_t)bh << 11) + qrow) * 64;
    bf16x8 qf0 = *(const bf16x8*)(Qh + qbase + G*8);
    bf16x8 qf1 = *(const bf16x8*)(Qh + qbase + 32 + G*8);
    const u64* brow = bits + (((size_t)(bh >> 3) << 11) + qrow) * 32;
    float rs = 0.f;
    for (int n0 = 0; n0 < 2048; n0 += 64) {
        f32x4 acc[4] = {};
        #pragma unroll
        for (int mt = 0; mt < 4; ++mt) {
            const size_t kb = ((((size_t)bh << 11) + n0 + mt*16 + q) * 64) + G*8;
            bf16x8 k0 = *(const bf16x8*)(Kh + kb);
            bf16x8 k1 = *(const bf16x8*)(Kh + kb + 32);
            acc[mt] = MFMA16(k0, qf0, acc[mt], 0, 0, 0);
            acc[mt] = MFMA16(k1, qf1, acc[mt], 0, 0, 0);
        }
        const u64 mw = brow[n0 >> 6];
        #pragma unroll
        for (int mt = 0; mt < 4; ++mt)
            #pragma unroll
            for (int r = 0; r < 4; ++r) {
                const int c = mt*16 + G*4 + r;
                const float e = exp2f(acc[mt][r] * L2E);
                rs += ((mw >> c) & 1) ? 0.f : e;
            }
    }
    rs += __shfl_xor(rs, 16);
    rs += __shfl_xor(rs, 32);
    if (G == 0) invs[((size_t)bh << 11) + qrow] = 1.0f / rs;
}

// ---------------- K3 (B): recompute E, write normalized attn once, accumulate PV ----------------
__global__ __launch_bounds__(256) void attnpv_kernel(
    const u16* __restrict__ Qh, const u16* __restrict__ Kh, const u16* __restrict__ Vt,
    const u64* __restrict__ bits, const float* __restrict__ invs,
    float* __restrict__ attn, u16* __restrict__ heads)
{
    const int qt = blockIdx.x, bh = blockIdx.y;
    const int b = bh >> 3, h = bh & 7;
    const int m0 = qt * 64;
    const int t = threadIdx.x, l = t & 63, w = t >> 6;
    const int q = l & 15, G = l >> 4;
    const int qrow = m0 + w*16 + q;
    __shared__ u16 alds[4][1024];          // per-wave 16x64 bf16 E tile, XOR-swizzled
    u16* my = alds[w];
    const size_t qbase = (((size_t)bh << 11) + qrow) * 64;
    bf16x8 qf0 = *(const bf16x8*)(Qh + qbase + G*8);
    bf16x8 qf1 = *(const bf16x8*)(Qh + qbase + 32 + G*8);
    const u64* brow = bits + (((size_t)b << 11) + qrow) * 32;
    const float inv = invs[((size_t)bh << 11) + qrow];
    float* arow = attn + (((size_t)bh << 11) + qrow) * 2048;
    const int swz = (q & 7) << 3;
    f32x4 pacc[4] = {};
    for (int n0 = 0; n0 < 2048; n0 += 64) {
        f32x4 acc[4] = {};
        #pragma unroll
        for (int mt = 0; mt < 4; ++mt) {
            const size_t kb = ((((size_t)bh << 11) + n0 + mt*16 + q) * 64) + G*8;
            bf16x8 k0 = *(const bf16x8*)(Kh + kb);
            bf16x8 k1 = *(const bf16x8*)(Kh + kb + 32);
            acc[mt] = MFMA16(k0, qf0, acc[mt], 0, 0, 0);
            acc[mt] = MFMA16(k1, qf1, acc[mt], 0, 0, 0);
        }
        const u64 mw = brow[n0 >> 6];
        #pragma unroll
        for (int mt = 0; mt < 4; ++mt) {
            float4 av;
            short4v sv;
            #pragma unroll
            for (int r = 0; r < 4; ++r) {
                const int c = mt*16 + G*4 + r;
                const float e = ((mw >> c) & 1) ? 0.f : exp2f(acc[mt][r] * L2E);
                const float a = e * inv;
                ((float*)&av)[r] = a;
                sv[r] = (short)f2bf(a);
            }
            *(float4*)(arow + n0 + mt*16 + G*4) = av;                   // normalized attn
            *(short4v*)&my[(q*64 + mt*16 + G*4) ^ swz] = sv;            // E for PV (lds)
        }
        __builtin_amdgcn_sched_barrier(0);
        bf16x8 an0 = *(const bf16x8*)&my[(q*64 +  0 + G*8) ^ swz];
        bf16x8 an1 = *(const bf16x8*)&my[(q*64 + 32 + G*8) ^ swz];
        #pragma unroll
        for (int dmt = 0; dmt < 4; ++dmt) {
            const size_t vb = ((((size_t)bh << 6) + dmt*16 + q) * 2048) + n0 + G*8;
            bf16x8 v0 = *(const bf16x8*)(Vt + vb);
            bf16x8 v1 = *(const bf16x8*)(Vt + vb + 32);
            pacc[dmt] = MFMA16(v0, an0, pacc[dmt], 0, 0, 0);
            pacc[dmt] = MFMA16(v1, an1, pacc[dmt], 0, 0, 0);
        }
    }
    #pragma unroll
    for (int dmt = 0; dmt < 4; ++dmt) {
        short4v sv;
        #pragma unroll
        for (int r = 0; r < 4; ++r) sv[r] = (short)f2bf(pacc[dmt][r]);
        *(short4v*)&heads[(((size_t)b << 11) + qrow) * 512 + h*64 + dmt*16 + G*4] = sv;
    }
}

// ---------------- K4: out = heads(bf16) @ wo + q residual ----------------
__global__ __launch_bounds__(256) void outgemm_kernel(
    const u16* __restrict__ heads, const u16* __restrict__ wt,
    const float* __restrict__ qin, float* __restrict__ out)
{
    const int m0 = blockIdx.x * 64, n0b = blockIdx.y * 64;
    const int t = threadIdx.x, l = t & 63, w = t >> 6;
    const int q = l & 15, G = l >> 4;
    const int wr = w >> 1, wc = w & 1;
    const u16* W = wt + (size_t)3 * 512 * 512;
    f32x4 acc[2][2] = {};
    for (int k0 = 0; k0 < 512; k0 += 32) {
        bf16x8 af[2], bfr[2];
        #pragma unroll
        for (int mi = 0; mi < 2; ++mi)
            af[mi] = *(const bf16x8*)(heads + (size_t)(m0 + wr*32 + mi*16 + q) * 512 + k0 + G*8);
        #pragma unroll
        for (int tn = 0; tn < 2; ++tn)
            bfr[tn] = *(const bf16x8*)(W + (size_t)(n0b + wc*32 + tn*16 + q) * 512 + k0 + G*8);
        #pragma unroll
        for (int mi = 0; mi < 2; ++mi)
            #pragma unroll
            for (int tn = 0; tn < 2; ++tn)
                acc[mi][tn] = MFMA16(af[mi], bfr[tn], acc[mi][tn], 0, 0, 0);
    }
    #pragma unroll
    for (int mi = 0; mi < 2; ++mi)
        #pragma unroll
        for (int r = 0; r < 4; ++r) {
            const int m = m0 + wr*32 + mi*16 + G*4 + r;
            #pragma unroll
            for (int tn = 0; tn < 2; ++tn) {
                const int n = n0b + wc*32 + tn*16 + q;
                out[(size_t)m * 512 + n] = acc[mi][tn][r] + qin[(size_t)m * 512 + n];
            }
        }
}

// ---------------- K5: in-place row LayerNorm ----------------
__global__ __launch_bounds__(256) void ln_kernel(
    float* __restrict__ out, const float* __restrict__ g, const float* __restrict__ be)
{
    const int m = blockIdx.x;
    float* row = out + (size_t)m * 512;
    const int t = threadIdx.x;
    float2 v = ((const float2*)row)[t];
    float s  = block_sum256(v.x + v.y);
    float s2 = block_sum256(v.x * v.x + v.y * v.y);
    const float mu  = s * (1.0f / 512.0f);
    const float var = s2 * (1.0f / 512.0f) - mu * mu;
    const float inv = rsqrtf(var + LN_EPS);
    float2 gg = ((const float2*)g)[t];
    float2 bb = ((const float2*)be)[t];
    float2 r;
    r.x = (v.x - mu) * inv * gg.x + bb.x;
    r.y = (v.y - mu) * inv * gg.y + bb.y;
    ((float2*)row)[t] = r;
}

// ---------------- launch ----------------
extern "C" void kernel_launch(void* const* d_in, const int* in_sizes, int n_in,
                              void* d_out, int out_size, void* d_ws, size_t ws_size,
                              hipStream_t stream) {
    const float* q   = (const float*)d_in[0];
    const float* k   = (const float*)d_in[1];
    const float* v   = (const float*)d_in[2];
    const float* wq  = (const float*)d_in[3];
    const float* wk  = (const float*)d_in[4];
    const float* wv  = (const float*)d_in[5];
    const float* wo  = (const float*)d_in[6];
    const float* g   = (const float*)d_in[7];
    const float* be  = (const float*)d_in[8];
    const int*   msk = (const int*)d_in[9];

    float* out  = (float*)d_out;
    float* attn = out + (size_t)4 * 2048 * 512;

    const size_t nQKV = (size_t)32 * 2048 * 64;     // 4M u16 per tensor
    u16* Qh    = (u16*)d_ws;
    u16* Kh    = Qh + nQKV;
    u16* Vh    = Kh + nQKV;
    u16* Vt    = Vh + nQKV;
    u16* heads = Vt + nQKV;
    u16* wt    = heads + (size_t)8192 * 512;
    u64* bits  = (u64*)(wt + (size_t)4 * 512 * 512);
    float* invs = (float*)(bits + (size_t)8192 * 32);

    prepw_kernel  <<<dim3(8, 8, 4),    256, 0, stream>>>(wq, wk, wv, wo, wt);
    prepm_kernel  <<<dim3(2048),       256, 0, stream>>>(msk, bits);
    proj_kernel   <<<dim3(128, 8, 3),  256, 0, stream>>>(q, k, v, wt, Qh, Kh, Vh);
    vt_kernel     <<<dim3(32, 32),     256, 0, stream>>>(Vh, Vt);
    rowsum_kernel <<<dim3(32, 32),     256, 0, stream>>>(Qh, Kh, bits, invs);
    attnpv_kernel <<<dim3(32, 32),     256, 0, stream>>>(Qh, Kh, Vt, bits, invs, attn, heads);
    outgemm_kernel<<<dim3(128, 8),     256, 0, stream>>>(heads, wt, q, out);
    ln_kernel     <<<dim3(8192),       256, 0, stream>>>(out, g, be);
}

// Round 4
// 657.162 us; speedup vs baseline: 1.8378x; 1.1323x over previous
//
#include <hip/hip_runtime.h>
#include <cstddef>

typedef __attribute__((ext_vector_type(8))) short bf16x8;
typedef __attribute__((ext_vector_type(4))) float f32x4;
typedef __attribute__((ext_vector_type(4))) short short4v;
typedef unsigned long long u64;
typedef unsigned int u32;
typedef unsigned short u16;

#define MFMA16 __builtin_amdgcn_mfma_f32_16x16x32_bf16
static constexpr float LN_EPS = 1e-5f;
static constexpr float L2E = 1.44269504f;

__device__ __forceinline__ u16 f2bf(float f) {
    u32 u = __builtin_bit_cast(u32, f);
    return (u16)((u + 0x7FFFu + ((u >> 16) & 1u)) >> 16);
}

// ---------------- block-wide sum (256 threads) ----------------
__device__ __forceinline__ float block_sum256(float v) {
    __shared__ float sc[4];
    #pragma unroll
    for (int o = 32; o > 0; o >>= 1) v += __shfl_down(v, o);
    if ((threadIdx.x & 63) == 0) sc[threadIdx.x >> 6] = v;
    __syncthreads();
    v = sc[0] + sc[1] + sc[2] + sc[3];
    __syncthreads();
    return v;
}

// ---------------- prep: weights fp32 [k][n] -> bf16 Wt [mat][n][k] ----------------
__global__ __launch_bounds__(256) void prepw_kernel(
    const float* __restrict__ wq, const float* __restrict__ wk,
    const float* __restrict__ wv, const float* __restrict__ wo,
    u16* __restrict__ wt)
{
    const int mat = blockIdx.z;
    const float* W = mat == 0 ? wq : mat == 1 ? wk : mat == 2 ? wv : wo;
    const int k0 = blockIdx.x * 64, n0 = blockIdx.y * 64;
    __shared__ u16 ld[64][72];
    const int t = threadIdx.x;
    {
        const int kk = t >> 2;
        #pragma unroll
        for (int j = 0; j < 4; ++j) {
            const int nn = ((t & 3) + j * 4) * 4;
            float4 x = *(const float4*)&W[(size_t)(k0 + kk) * 512 + n0 + nn];
            ld[kk][nn + 0] = f2bf(x.x); ld[kk][nn + 1] = f2bf(x.y);
            ld[kk][nn + 2] = f2bf(x.z); ld[kk][nn + 3] = f2bf(x.w);
        }
    }
    __syncthreads();
    {
        const int n = t & 63, kc = (t >> 6) * 16;
        u16* op = wt + ((size_t)mat * 512 + n0 + n) * 512 + k0 + kc;
        #pragma unroll
        for (int j = 0; j < 4; ++j) {
            short4v v;
            v[0] = ld[kc + j*4 + 0][n]; v[1] = ld[kc + j*4 + 1][n];
            v[2] = ld[kc + j*4 + 2][n]; v[3] = ld[kc + j*4 + 3][n];
            *(short4v*)(op + j * 4) = v;
        }
    }
}

// ---------------- prep: mask int32 -> bit-packed u64 [8192 rows][32 words] ----------------
__global__ __launch_bounds__(256) void prepm_kernel(
    const int* __restrict__ mask, u64* __restrict__ bits)
{
    const int t = threadIdx.x;
    const int row = blockIdx.x * 4 + (t >> 6);
    const int wl = t & 63;
    const int* mrow = mask + (size_t)row * 2048;
    u64* brow = bits + (size_t)row * 32;
    #pragma unroll 8
    for (int it = 0; it < 32; ++it) {
        u64 b = __ballot(mrow[it * 64 + wl] != 0);
        if (wl == 0) brow[it] = b;
    }
}

// ---------------- K1: projections via MFMA. X fp32 @ Wt -> Qh/Kh/Vh bf16 [bh][s][64]
__global__ __launch_bounds__(256) void proj_kernel(
    const float* __restrict__ qin, const float* __restrict__ kin, const float* __restrict__ vin,
    const u16* __restrict__ wt,
    u16* __restrict__ Qh, u16* __restrict__ Kh, u16* __restrict__ Vh)
{
    const int z = blockIdx.z;
    const float* X = z == 0 ? qin : (z == 1 ? kin : vin);
    const u16* W = wt + (size_t)z * 512 * 512;
    u16* O = z == 0 ? Qh : (z == 1 ? Kh : Vh);
    const int m0 = blockIdx.x * 64;
    const int h = blockIdx.y;
    const int t = threadIdx.x, l = t & 63, w = t >> 6;
    const int q = l & 15, G = l >> 4;
    const int wr = w >> 1, wc = w & 1;

    f32x4 acc[2][2] = {};
    for (int k0 = 0; k0 < 512; k0 += 32) {
        bf16x8 af[2], bfr[2];
        #pragma unroll
        for (int mi = 0; mi < 2; ++mi) {
            const float* xp = X + (size_t)(m0 + wr*32 + mi*16 + q) * 512 + k0 + G*8;
            float4 x0 = *(const float4*)xp;
            float4 x1 = *(const float4*)(xp + 4);
            bf16x8 a;
            a[0] = f2bf(x0.x); a[1] = f2bf(x0.y); a[2] = f2bf(x0.z); a[3] = f2bf(x0.w);
            a[4] = f2bf(x1.x); a[5] = f2bf(x1.y); a[6] = f2bf(x1.z); a[7] = f2bf(x1.w);
            af[mi] = a;
        }
        #pragma unroll
        for (int tn = 0; tn < 2; ++tn)
            bfr[tn] = *(const bf16x8*)(W + (size_t)(h*64 + wc*32 + tn*16 + q) * 512 + k0 + G*8);
        #pragma unroll
        for (int mi = 0; mi < 2; ++mi)
            #pragma unroll
            for (int tn = 0; tn < 2; ++tn)
                acc[mi][tn] = MFMA16(af[mi], bfr[tn], acc[mi][tn], 0, 0, 0);
    }
    const float scv = (z == 0) ? 0.125f : 1.0f;   // fold 1/sqrt(64) into Q (exact pow2)
    #pragma unroll
    for (int mi = 0; mi < 2; ++mi)
        #pragma unroll
        for (int tn = 0; tn < 2; ++tn)
            #pragma unroll
            for (int r = 0; r < 4; ++r) {
                const int m = m0 + wr*32 + mi*16 + G*4 + r;
                const int b = m >> 11, s = m & 2047;
                const int d = wc*32 + tn*16 + q;
                O[(((size_t)(b*8 + h) << 11) + s) * 64 + d] = f2bf(acc[mi][tn][r] * scv);
            }
}

// ---------------- V transpose: Vh [bh][s][64] -> Vt [bh][64][2048] ----------------
__global__ __launch_bounds__(256) void vt_kernel(
    const u16* __restrict__ Vh, u16* __restrict__ Vt)
{
    const int bh = blockIdx.y, s0 = blockIdx.x * 64;
    __shared__ u16 ld[64][72];
    const int t = threadIdx.x;
    {
        const int s = t >> 2, dg = (t & 3) * 16;
        const u16* vp = Vh + ((((size_t)bh << 11) + s0 + s) * 64) + dg;
        *(bf16x8*)&ld[s][dg]     = *(const bf16x8*)vp;
        *(bf16x8*)&ld[s][dg + 8] = *(const bf16x8*)(vp + 8);
    }
    __syncthreads();
    {
        const int d = t & 63, sc = (t >> 6) * 16;
        u16* op = Vt + (((size_t)bh << 6) + d) * 2048 + s0 + sc;
        #pragma unroll
        for (int j = 0; j < 4; ++j) {
            short4v v;
            v[0] = ld[sc + j*4 + 0][d]; v[1] = ld[sc + j*4 + 1][d];
            v[2] = ld[sc + j*4 + 2][d]; v[3] = ld[sc + j*4 + 3][d];
            *(short4v*)(op + j * 4) = v;
        }
    }
}

// ---------------- K2 (A): row sums of exp via swapped MFMA S^T = K·Q^T ----------------
__global__ __launch_bounds__(256) void rowsum_kernel(
    const u16* __restrict__ Qh, const u16* __restrict__ Kh,
    const u64* __restrict__ bits, float* __restrict__ invs)
{
    const int qt = blockIdx.x, bh = blockIdx.y;
    const int m0 = qt * 64;
    const int t = threadIdx.x, l = t & 63, w = t >> 6;
    const int q = l & 15, G = l >> 4;
    const int qrow = m0 + w*16 + q;
    const size_t qbase = (((size_t)bh << 11) + qrow) * 64;
    bf16x8 qf0 = *(const bf16x8*)(Qh + qbase + G*8);
    bf16x8 qf1 = *(const bf16x8*)(Qh + qbase + 32 + G*8);
    const u64* brow = bits + (((size_t)(bh >> 3) << 11) + qrow) * 32;
    float rs = 0.f;
    for (int n0 = 0; n0 < 2048; n0 += 64) {
        f32x4 acc[4] = {};
        #pragma unroll
        for (int mt = 0; mt < 4; ++mt) {
            const size_t kb = ((((size_t)bh << 11) + n0 + mt*16 + q) * 64) + G*8;
            bf16x8 k0 = *(const bf16x8*)(Kh + kb);
            bf16x8 k1 = *(const bf16x8*)(Kh + kb + 32);
            acc[mt] = MFMA16(k0, qf0, acc[mt], 0, 0, 0);
            acc[mt] = MFMA16(k1, qf1, acc[mt], 0, 0, 0);
        }
        const u64 mw = brow[n0 >> 6];
        #pragma unroll
        for (int mt = 0; mt < 4; ++mt)
            #pragma unroll
            for (int r = 0; r < 4; ++r) {
                const int c = mt*16 + G*4 + r;
                const float e = exp2f(acc[mt][r] * L2E);
                rs += ((mw >> c) & 1) ? 0.f : e;
            }
    }
    rs += __shfl_xor(rs, 16);
    rs += __shfl_xor(rs, 32);
    if (G == 0) invs[((size_t)bh << 11) + qrow] = 1.0f / rs;
}

// ---------------- K3 (B): recompute E, buffer normalized attn in LDS, flush 1KB bursts, accumulate PV
__global__ __launch_bounds__(256) void attnpv_kernel(
    const u16* __restrict__ Qh, const u16* __restrict__ Kh, const u16* __restrict__ Vt,
    const u64* __restrict__ bits, const float* __restrict__ invs,
    float* __restrict__ attn, u16* __restrict__ heads)
{
    const int qt = blockIdx.x, bh = blockIdx.y;
    const int b = bh >> 3, h = bh & 7;
    const int m0 = qt * 64;
    const int t = threadIdx.x, l = t & 63, w = t >> 6;
    const int q = l & 15, G = l >> 4;
    const int qrow = m0 + w*16 + q;
    const int lrow = w*16 + q;
    __shared__ u16 alds[4][1024];          // per-wave 16x64 bf16 E tile, XOR-swizzled
    __shared__ float fbuf[64][264];        // 64 rows x 256 cols f32 attn staging (+8 pad)
    u16* my = alds[w];
    const size_t qbase = (((size_t)bh << 11) + qrow) * 64;
    bf16x8 qf0 = *(const bf16x8*)(Qh + qbase + G*8);
    bf16x8 qf1 = *(const bf16x8*)(Qh + qbase + 32 + G*8);
    const u64* brow = bits + (((size_t)b << 11) + qrow) * 32;
    const float inv = invs[((size_t)bh << 11) + qrow];
    const int swz = (q & 7) << 3;
    f32x4 pacc[4] = {};
    for (int n0 = 0; n0 < 2048; n0 += 64) {
        const int cb = ((n0 >> 6) & 3) * 64;
        f32x4 acc[4] = {};
        #pragma unroll
        for (int mt = 0; mt < 4; ++mt) {
            const size_t kb = ((((size_t)bh << 11) + n0 + mt*16 + q) * 64) + G*8;
            bf16x8 k0 = *(const bf16x8*)(Kh + kb);
            bf16x8 k1 = *(const bf16x8*)(Kh + kb + 32);
            acc[mt] = MFMA16(k0, qf0, acc[mt], 0, 0, 0);
            acc[mt] = MFMA16(k1, qf1, acc[mt], 0, 0, 0);
        }
        const u64 mw = brow[n0 >> 6];
        #pragma unroll
        for (int mt = 0; mt < 4; ++mt) {
            float4 av;
            short4v sv;
            #pragma unroll
            for (int r = 0; r < 4; ++r) {
                const int c = mt*16 + G*4 + r;
                const float e = ((mw >> c) & 1) ? 0.f : exp2f(acc[mt][r] * L2E);
                const float a = e * inv;
                ((float*)&av)[r] = a;
                sv[r] = (short)f2bf(a);
            }
            *(float4*)&fbuf[lrow][cb + mt*16 + G*4] = av;               // staged attn
            *(short4v*)&my[(q*64 + mt*16 + G*4) ^ swz] = sv;            // E for PV (lds)
        }
        bf16x8 an0 = *(const bf16x8*)&my[(q*64 +  0 + G*8) ^ swz];
        bf16x8 an1 = *(const bf16x8*)&my[(q*64 + 32 + G*8) ^ swz];
        #pragma unroll
        for (int dmt = 0; dmt < 4; ++dmt) {
            const size_t vb = ((((size_t)bh << 6) + dmt*16 + q) * 2048) + n0 + G*8;
            bf16x8 v0 = *(const bf16x8*)(Vt + vb);
            bf16x8 v1 = *(const bf16x8*)(Vt + vb + 32);
            pacc[dmt] = MFMA16(v0, an0, pacc[dmt], 0, 0, 0);
            pacc[dmt] = MFMA16(v1, an1, pacc[dmt], 0, 0, 0);
        }
        if ((n0 & 192) == 192) {
            // flush 4 staged K-tiles: 16 rows/wave, 1KB contiguous per store
            const int c0 = n0 - 192;
            float* ab = attn + (((size_t)bh << 11) + m0 + w*16) * 2048 + c0;
            #pragma unroll
            for (int r = 0; r < 16; ++r) {
                float4 vv = *(const float4*)&fbuf[w*16 + r][l*4];
                *(float4*)(ab + (size_t)r * 2048 + l*4) = vv;
            }
        }
    }
    #pragma unroll
    for (int dmt = 0; dmt < 4; ++dmt) {
        short4v sv;
        #pragma unroll
        for (int r = 0; r < 4; ++r) sv[r] = (short)f2bf(pacc[dmt][r]);
        *(short4v*)&heads[(((size_t)b << 11) + qrow) * 512 + h*64 + dmt*16 + G*4] = sv;
    }
}

// ---------------- K4: out = heads(bf16) @ wo + q residual ----------------
__global__ __launch_bounds__(256) void outgemm_kernel(
    const u16* __restrict__ heads, const u16* __restrict__ wt,
    const float* __restrict__ qin, float* __restrict__ out)
{
    const int m0 = blockIdx.x * 64, n0b = blockIdx.y * 64;
    const int t = threadIdx.x, l = t & 63, w = t >> 6;
    const int q = l & 15, G = l >> 4;
    const int wr = w >> 1, wc = w & 1;
    const u16* W = wt + (size_t)3 * 512 * 512;
    f32x4 acc[2][2] = {};
    for (int k0 = 0; k0 < 512; k0 += 32) {
        bf16x8 af[2], bfr[2];
        #pragma unroll
        for (int mi = 0; mi < 2; ++mi)
            af[mi] = *(const bf16x8*)(heads + (size_t)(m0 + wr*32 + mi*16 + q) * 512 + k0 + G*8);
        #pragma unroll
        for (int tn = 0; tn < 2; ++tn)
            bfr[tn] = *(const bf16x8*)(W + (size_t)(n0b + wc*32 + tn*16 + q) * 512 + k0 + G*8);
        #pragma unroll
        for (int mi = 0; mi < 2; ++mi)
            #pragma unroll
            for (int tn = 0; tn < 2; ++tn)
                acc[mi][tn] = MFMA16(af[mi], bfr[tn], acc[mi][tn], 0, 0, 0);
    }
    #pragma unroll
    for (int mi = 0; mi < 2; ++mi)
        #pragma unroll
        for (int r = 0; r < 4; ++r) {
            const int m = m0 + wr*32 + mi*16 + G*4 + r;
            #pragma unroll
            for (int tn = 0; tn < 2; ++tn) {
                const int n = n0b + wc*32 + tn*16 + q;
                out[(size_t)m * 512 + n] = acc[mi][tn][r] + qin[(size_t)m * 512 + n];
            }
        }
}

// ---------------- K5: in-place row LayerNorm ----------------
__global__ __launch_bounds__(256) void ln_kernel(
    float* __restrict__ out, const float* __restrict__ g, const float* __restrict__ be)
{
    const int m = blockIdx.x;
    float* row = out + (size_t)m * 512;
    const int t = threadIdx.x;
    float2 v = ((const float2*)row)[t];
    float s  = block_sum256(v.x + v.y);
    float s2 = block_sum256(v.x * v.x + v.y * v.y);
    const float mu  = s * (1.0f / 512.0f);
    const float var = s2 * (1.0f / 512.0f) - mu * mu;
    const float inv = rsqrtf(var + LN_EPS);
    float2 gg = ((const float2*)g)[t];
    float2 bb = ((const float2*)be)[t];
    float2 r;
    r.x = (v.x - mu) * inv * gg.x + bb.x;
    r.y = (v.y - mu) * inv * gg.y + bb.y;
    ((float2*)row)[t] = r;
}

// ---------------- launch ----------------
extern "C" void kernel_launch(void* const* d_in, const int* in_sizes, int n_in,
                              void* d_out, int out_size, void* d_ws, size_t ws_size,
                              hipStream_t stream) {
    const float* q   = (const float*)d_in[0];
    const float* k   = (const float*)d_in[1];
    const float* v   = (const float*)d_in[2];
    const float* wq  = (const float*)d_in[3];
    const float* wk  = (const float*)d_in[4];
    const float* wv  = (const float*)d_in[5];
    const float* wo  = (const float*)d_in[6];
    const float* g   = (const float*)d_in[7];
    const float* be  = (const float*)d_in[8];
    const int*   msk = (const int*)d_in[9];

    float* out  = (float*)d_out;
    float* attn = out + (size_t)4 * 2048 * 512;

    const size_t nQKV = (size_t)32 * 2048 * 64;     // 4M u16 per tensor
    u16* Qh    = (u16*)d_ws;
    u16* Kh    = Qh + nQKV;
    u16* Vh    = Kh + nQKV;
    u16* Vt    = Vh + nQKV;
    u16* heads = Vt + nQKV;
    u16* wt    = heads + (size_t)8192 * 512;
    u64* bits  = (u64*)(wt + (size_t)4 * 512 * 512);
    float* invs = (float*)(bits + (size_t)8192 * 32);

    prepw_kernel  <<<dim3(8, 8, 4),    256, 0, stream>>>(wq, wk, wv, wo, wt);
    prepm_kernel  <<<dim3(2048),       256, 0, stream>>>(msk, bits);
    proj_kernel   <<<dim3(128, 8, 3),  256, 0, stream>>>(q, k, v, wt, Qh, Kh, Vh);
    vt_kernel     <<<dim3(32, 32),     256, 0, stream>>>(Vh, Vt);
    rowsum_kernel <<<dim3(32, 32),     256, 0, stream>>>(Qh, Kh, bits, invs);
    attnpv_kernel <<<dim3(32, 32),     256, 0, stream>>>(Qh, Kh, Vt, bits, invs, attn, heads);
    outgemm_kernel<<<dim3(128, 8),     256, 0, stream>>>(heads, wt, q, out);
    ln_kernel     <<<dim3(8192),       256, 0, stream>>>(out, g, be);
}